// Round 10
// baseline (54.081 us; speedup 1.0000x reference)
//
#include <hip/hip_runtime.h>
#include <hip/hip_bf16.h>
#include <stdint.h>

// out[b,o,p] = sum_{r,c} mat0[b,c,p] * mat1[o,c,r]*Alpha[r] * mask[r,p]
// GEMM: M=256 (o), N=32768 (n=b*4096+p), K=2048 (k=c*8+r).
// A[o,k] = mat1[o,c,r]*Alpha[r]  (prepped FP16 in d_ws, layout [c][o][8r])
// B[k,n] = mat0[b,c,p]*mask[r,p] synthesized IN REGISTERS per lane (fp16).
// Round 10: BARRIER-FREE. R9's pipes (MFMA 1033 + LDS 1130 + VALU 640 +
// VMEM ~300 cyc/CU-round) ran serially because the block barrier locks all
// waves into the same phase. Fix: wave-PRIVATE A-slabs (each wave stages its
// own 64 rows x 8 c-planes = 8KB via global_load_lds, double-buffered) ->
// producer == consumer -> sync is just the wave's own counted vmcnt. Zero
// barriers; waves free-run and de-phase. + T5 setprio around MFMA quads.

typedef __attribute__((ext_vector_type(8)))  _Float16 half8;
typedef __attribute__((ext_vector_type(16))) float    f32x16;

#define C_IN  256
#define HW_   4096
#define NRND  32    // K rounds of 64 (8 c-planes per round)

__global__ __launch_bounds__(256) void prep_w_kernel(
    const float* __restrict__ mat1, const float* __restrict__ Alpha,
    const int* __restrict__ use_alpha, _Float16* __restrict__ Aprep) {
  int t = blockIdx.x * 256 + threadIdx.x;   // o = t&255, c = t>>8
  int o = t & 255;
  int c = t >> 8;
  int ua = use_alpha[0];
  const float* src = mat1 + ((size_t)o * C_IN + c) * 8;
  half8 v;
#pragma unroll
  for (int r = 0; r < 8; ++r) {
    float s = ua ? Alpha[r] : 1.0f;
    v[r] = (_Float16)(src[r] * s);
  }
  // layout: slot (c*256 + o) holds 8 fp16 (r fastest)
  *(half8*)(Aprep + ((size_t)c * 256 + o) * 8) = v;
}

__global__ __launch_bounds__(256, 2) void gemm_deform_kernel(
    const float* __restrict__ mat0, const _Float16* __restrict__ Aprep,
    const float* __restrict__ mask, float* __restrict__ out) {
  // wave-private slabs: [buf][wave][slot], slot = cq*64 + rr (16B slots)
  __shared__ half8 A_lds[2][4][512];   // 64 KiB

  int bid = blockIdx.x;
  int wg = (bid & 7) * 64 + (bid >> 3);   // XCD swizzle (512%8==0, bijective)
  int tile_m = wg & 1;                    // M fastest: pair shares mat0 cols
  int tile_n = wg >> 1;                   // 0..255
  int o0 = tile_m * 128;
  int n0 = tile_n * 128;
  int b  = n0 >> 12;
  int p0 = n0 & 4095;

  int t    = threadIdx.x;
  int lane = t & 63;
  int w    = t >> 6;        // 0..3
  int wc   = w & 1;         // N-half (64 cols)
  int wr   = w >> 1;        // M-half (64 rows)
  int l31  = lane & 31;
  int cr   = lane >> 5;     // c-plane parity within MFMA K=16

  // this wave's two 32-col groups; lane-resident packed fp16 mask
  int colb = p0 + wc * 64 + l31;
  half8 mkh[2];
#pragma unroll
  for (int ni = 0; ni < 2; ++ni)
#pragma unroll
    for (int r = 0; r < 8; ++r)
      mkh[ni][r] = (_Float16)mask[r * HW_ + colb + ni * 32];

  // mat0 scalar source: plane c = rd*8 + kq*2 + cr, columns colb, colb+32
  const float* __restrict__ m0b =
      mat0 + ((size_t)b * C_IN + cr) * HW_ + colb;

  // A staging: this wave's 64 rows (o0+wr*64..+63), 8 c-planes per round
  const __attribute__((address_space(1))) uint32_t* gA =
      (const __attribute__((address_space(1))) uint32_t*)Aprep;
  __attribute__((address_space(3))) uint32_t* lA =
      (__attribute__((address_space(3))) uint32_t*)&A_lds[0][0][0];
  int arow = o0 + wr * 64 + lane;   // this lane's staged A-row

  f32x16 acc[2][2];   // [mi][ni]
#pragma unroll
  for (int mi = 0; mi < 2; ++mi)
#pragma unroll
    for (int ni = 0; ni < 2; ++ni)
#pragma unroll
      for (int j = 0; j < 16; ++j) acc[mi][ni][j] = 0.f;

  float P0[4][2], P1[4][2];   // [kq][ni] mat0 scalars, ping-pong by parity

  // stage this wave's private slab for round rd into buf (8 gload_lds)
  auto STAGE = [&](int rd, int buf) {
#pragma unroll
    for (int i = 0; i < 8; ++i) {
      int gslot = (rd * 8 + i) * 256 + arow;          // cq = i, row = lane
      int lslot = (buf * 4 + w) * 512 + i * 64;       // +lane by HW
      __builtin_amdgcn_global_load_lds(gA + (size_t)gslot * 4,
                                       lA + (size_t)lslot * 4, 16, 0, 0);
    }
  };

  auto LOADP = [&](float (&P)[4][2], int rd) {   // 8 loads
    const float* mp = m0b + (size_t)(rd * 8) * HW_;
#pragma unroll
    for (int kq = 0; kq < 4; ++kq) {
      P[kq][0] = mp[(size_t)(kq * 2) * HW_];
      P[kq][1] = mp[(size_t)(kq * 2) * HW_ + 32];
    }
  };

  // compute round rd from private slab in buf; refill P for rd+2 (clamped)
  auto COMP = [&](const half8* __restrict__ Abuf, float (&P)[4][2], int rd) {
    int rp = rd + 2 > 31 ? 31 : rd + 2;
    const float* mnext = m0b + (size_t)(rp * 8) * HW_;
#pragma unroll
    for (int kq = 0; kq < 4; ++kq) {
      half8 a0 = Abuf[(kq * 2 + cr) * 64 + l31];
      half8 a1 = Abuf[(kq * 2 + cr) * 64 + 32 + l31];
      _Float16 h0 = (_Float16)P[kq][0];
      _Float16 h1 = (_Float16)P[kq][1];
      half8 pb0 = {h0, h0, h0, h0, h0, h0, h0, h0};
      half8 pb1 = {h1, h1, h1, h1, h1, h1, h1, h1};
      half8 bv0 = pb0 * mkh[0];   // 4x v_pk_mul_f16
      half8 bv1 = pb1 * mkh[1];
      __builtin_amdgcn_s_setprio(1);
      acc[0][0] = __builtin_amdgcn_mfma_f32_32x32x16_f16(a0, bv0, acc[0][0], 0, 0, 0);
      acc[0][1] = __builtin_amdgcn_mfma_f32_32x32x16_f16(a0, bv1, acc[0][1], 0, 0, 0);
      acc[1][0] = __builtin_amdgcn_mfma_f32_32x32x16_f16(a1, bv0, acc[1][0], 0, 0, 0);
      acc[1][1] = __builtin_amdgcn_mfma_f32_32x32x16_f16(a1, bv1, acc[1][1], 0, 0, 0);
      __builtin_amdgcn_s_setprio(0);
      // refill this kq's P for round rd+2 (stays in flight, wave-local)
      P[kq][0] = mnext[(size_t)(kq * 2) * HW_];
      P[kq][1] = mnext[(size_t)(kq * 2) * HW_ + 32];
    }
  };

  const half8* buf0 = &A_lds[0][0][0] + w * 512;
  const half8* buf1 = &A_lds[1][0][0] + w * 512;

  // ---- prologue (no barrier anywhere) ----
  STAGE(0, 0);       // 8 outstanding
  LOADP(P0, 0);      // +8
  LOADP(P1, 1);      // +8 -> 24

  // ---- main loop: wave-private sync only; vmcnt never drains to 0 ----
#pragma unroll 1
  for (int rd = 0; rd < NRND; rd += 2) {
    STAGE(rd + 1, 1);                                   // +8
    asm volatile("s_waitcnt vmcnt(16)" ::: "memory");   // stage(rd) landed
    COMP(buf0, P0, rd);                                 // +8 P0 refill
    STAGE(rd + 2 > 31 ? 31 : rd + 2, 0);                // +8 (last: dummy restage)
    asm volatile("s_waitcnt vmcnt(16)" ::: "memory");   // stage(rd+1) landed
    COMP(buf1, P1, rd + 1);                             // +8 P1 refill
  }

  // ---- epilogue: 32x32 C/D layout col=lane&31, row=(reg&3)+8*(reg>>2)+4*cr ----
  size_t obase = (size_t)b * 256 * HW_ + colb;
#pragma unroll
  for (int mi = 0; mi < 2; ++mi) {
#pragma unroll
    for (int ni = 0; ni < 2; ++ni) {
#pragma unroll
      for (int reg = 0; reg < 16; ++reg) {
        int row = o0 + wr * 64 + mi * 32 + (reg & 3) + 8 * (reg >> 2) + 4 * cr;
        out[obase + (size_t)row * HW_ + ni * 32] = acc[mi][ni][reg];
      }
    }
  }
}

extern "C" void kernel_launch(void* const* d_in, const int* in_sizes, int n_in,
                              void* d_out, int out_size, void* d_ws, size_t ws_size,
                              hipStream_t stream) {
  const float* mat0      = (const float*)d_in[0];   // [8,256,64,64]
  const float* mat1      = (const float*)d_in[1];   // [256,256,8]
  const float* mask      = (const float*)d_in[2];   // [8,64,64]
  const float* Alpha     = (const float*)d_in[3];   // [8]
  const int*   use_alpha = (const int*)d_in[4];     // [1]
  (void)in_sizes; (void)n_in; (void)out_size; (void)ws_size;

  _Float16* Aprep = (_Float16*)d_ws;                // 1 MiB scratch
  float* outp  = (float*)d_out;

  prep_w_kernel<<<256, 256, 0, stream>>>(mat1, Alpha, use_alpha, Aprep);
  gemm_deform_kernel<<<512, 256, 0, stream>>>(mat0, Aprep, mask, outp);
}

// Round 11
// 50.685 us; speedup vs baseline: 1.0670x; 1.0670x over previous
//
#include <hip/hip_runtime.h>
#include <hip/hip_bf16.h>
#include <stdint.h>

// out[b,o,p] = sum_{r,c} mat0[b,c,p] * mat1[o,c,r]*Alpha[r] * mask[r,p]
// GEMM: M=256 (o), N=32768 (n=b*4096+p), K=2048 (k=c*8+r).
// A[o,k] = mat1[o,c,r]*Alpha[r]  (prepped FP16 in d_ws, layout [c][o][8r])
// B[k,n] = mat0[b,c,p]*mask[r,p] synthesized IN REGISTERS per lane (fp16).
// Round 11 = R9 geometry + 4-PHASE INTERLEAVED schedule (T3+T4+T5):
// each kq-phase = {1 gload_lds(rd+1) | 2 ds_read a-pair | barrier |
// synth | setprio(1) 4xMFMA setprio(0) | 2 P-refill}; round end = single
// counted s_waitcnt vmcnt(2) + barrier (stage DMAs drained, P-pair in
// flight). R9's coarse phases ran the pipes serially (~3375 cyc/round vs
// ~1100 ideal); the fine interleave is the proven lever (m196/m218/m233).

typedef __attribute__((ext_vector_type(8)))  _Float16 half8;
typedef __attribute__((ext_vector_type(16))) float    f32x16;

#define C_IN  256
#define HW_   4096
#define NRND  32    // K rounds of 64 (8 c-planes per round)

__global__ __launch_bounds__(256) void prep_w_kernel(
    const float* __restrict__ mat1, const float* __restrict__ Alpha,
    const int* __restrict__ use_alpha, _Float16* __restrict__ Aprep) {
  int t = blockIdx.x * 256 + threadIdx.x;   // o = t&255, c = t>>8
  int o = t & 255;
  int c = t >> 8;
  int ua = use_alpha[0];
  const float* src = mat1 + ((size_t)o * C_IN + c) * 8;
  half8 v;
#pragma unroll
  for (int r = 0; r < 8; ++r) {
    float s = ua ? Alpha[r] : 1.0f;
    v[r] = (_Float16)(src[r] * s);
  }
  // layout: slot (c*256 + o) holds 8 fp16 (r fastest)
  *(half8*)(Aprep + ((size_t)c * 256 + o) * 8) = v;
}

__global__ __launch_bounds__(256, 2) void gemm_deform_kernel(
    const float* __restrict__ mat0, const _Float16* __restrict__ Aprep,
    const float* __restrict__ mask, float* __restrict__ out) {
  // A slab per round: 8 c-planes x 128 rows, slot = cq*128 + (o-o0), 16B slots
  __shared__ half8 A_lds[2][1024];   // 2 x 16 KiB double buffer

  int bid = blockIdx.x;
  int wg = (bid & 7) * 64 + (bid >> 3);   // XCD swizzle (512%8==0, bijective)
  int tile_m = wg & 1;                    // M fastest: pair shares mat0 cols
  int tile_n = wg >> 1;                   // 0..255
  int o0 = tile_m * 128;
  int n0 = tile_n * 128;
  int b  = n0 >> 12;
  int p0 = n0 & 4095;

  int t    = threadIdx.x;
  int lane = t & 63;
  int w    = t >> 6;        // 0..3
  int wc   = w & 1;         // N-half (64 cols)
  int wr   = w >> 1;        // M-half (64 rows)
  int l31  = lane & 31;
  int cr   = lane >> 5;     // c-plane parity within MFMA K=16

  // this wave's two 32-col groups; lane-resident packed fp16 mask
  int colb = p0 + wc * 64 + l31;
  half8 mkh[2];
#pragma unroll
  for (int ni = 0; ni < 2; ++ni)
#pragma unroll
    for (int r = 0; r < 8; ++r)
      mkh[ni][r] = (_Float16)mask[r * HW_ + colb + ni * 32];

  // mat0 scalar source: plane c = rd*8 + kq*2 + cr, columns colb, colb+32
  const float* __restrict__ m0b =
      mat0 + ((size_t)b * C_IN + cr) * HW_ + colb;

  // A staging: global slot (16B units) in Aprep; LDS dest wave-uniform base
  const __attribute__((address_space(1))) uint32_t* gA =
      (const __attribute__((address_space(1))) uint32_t*)Aprep;
  __attribute__((address_space(3))) uint32_t* lA =
      (__attribute__((address_space(3))) uint32_t*)&A_lds[0][0];
  int soo  = (w & 1) * 64 + lane;   // column part of this thread's src slot
  int scqb = w >> 1;                // c-plane parity of this thread's src slot

  f32x16 acc[2][2];   // [mi][ni]
#pragma unroll
  for (int mi = 0; mi < 2; ++mi)
#pragma unroll
    for (int ni = 0; ni < 2; ++ni)
#pragma unroll
      for (int j = 0; j < 16; ++j) acc[mi][ni][j] = 0.f;

  float P[4][2];   // [kq][ni] mat0 scalars, refilled in place per phase

  // ---- prologue: stage round 0 (4 DMAs), load P for round 0 (8 loads) ----
#pragma unroll
  for (int i = 0; i < 4; ++i) {
    int gslot = (0 * 8 + i * 2 + scqb) * 256 + o0 + soo;
    __builtin_amdgcn_global_load_lds(gA + (size_t)gslot * 4,
                                     lA + (size_t)(i * 256 + w * 64) * 4,
                                     16, 0, 0);
  }
#pragma unroll
  for (int kq = 0; kq < 4; ++kq) {
    P[kq][0] = m0b[(size_t)(kq * 2) * HW_];
    P[kq][1] = m0b[(size_t)(kq * 2) * HW_ + 32];
  }
  asm volatile("s_waitcnt vmcnt(8)" ::: "memory");   // stage(0) landed
  __builtin_amdgcn_s_barrier();

  // ---- main loop: 4 interleaved phases per round ----
#pragma unroll 1
  for (int rd = 0; rd < NRND; ++rd) {
    const half8* __restrict__ Abuf = &A_lds[rd & 1][0];
    int bufn = (rd & 1) ^ 1;
    int rs = rd + 1 > 31 ? 31 : rd + 1;   // staged round (dummy restage at tail)
    int gbase = rs * 8;
#pragma unroll
    for (int p = 0; p < 4; ++p) {
      // (1) stage one DMA for rd+1 into the other buffer
      int gslot = (gbase + p * 2 + scqb) * 256 + o0 + soo;
      __builtin_amdgcn_global_load_lds(gA + (size_t)gslot * 4,
                                       lA + (size_t)(bufn * 1024 + p * 256 + w * 64) * 4,
                                       16, 0, 0);
      // (2) a-pair for this kq from current buffer
      half8 a0 = Abuf[(p * 2 + cr) * 128 + wr * 64 + l31];
      half8 a1 = Abuf[(p * 2 + cr) * 128 + wr * 64 + 32 + l31];
      // (3) rhythm barrier: waves enter MFMA together, loads in flight
      __builtin_amdgcn_s_barrier();
      // (4) synth B fragments (fp16 packed muls)
      _Float16 h0 = (_Float16)P[p][0];
      _Float16 h1 = (_Float16)P[p][1];
      half8 pb0 = {h0, h0, h0, h0, h0, h0, h0, h0};
      half8 pb1 = {h1, h1, h1, h1, h1, h1, h1, h1};
      half8 bv0 = pb0 * mkh[0];
      half8 bv1 = pb1 * mkh[1];
      // (5) MFMA cluster
      __builtin_amdgcn_s_setprio(1);
      acc[0][0] = __builtin_amdgcn_mfma_f32_32x32x16_f16(a0, bv0, acc[0][0], 0, 0, 0);
      acc[0][1] = __builtin_amdgcn_mfma_f32_32x32x16_f16(a0, bv1, acc[0][1], 0, 0, 0);
      acc[1][0] = __builtin_amdgcn_mfma_f32_32x32x16_f16(a1, bv0, acc[1][0], 0, 0, 0);
      acc[1][1] = __builtin_amdgcn_mfma_f32_32x32x16_f16(a1, bv1, acc[1][1], 0, 0, 0);
      __builtin_amdgcn_s_setprio(0);
      // (6) refill this kq's P for rd+1 (stays in flight across round end)
      const float* mnext = m0b + (size_t)(gbase + p * 2) * HW_;
      P[p][0] = mnext[0];
      P[p][1] = mnext[32];
    }
    // round end: drain this round's 4 stage-DMAs, keep last P-pair in flight
    asm volatile("s_waitcnt vmcnt(2)" ::: "memory");
    __builtin_amdgcn_s_barrier();
  }

  // ---- epilogue: 32x32 C/D layout col=lane&31, row=(reg&3)+8*(reg>>2)+4*cr ----
  size_t obase = (size_t)b * 256 * HW_ + colb;
#pragma unroll
  for (int mi = 0; mi < 2; ++mi) {
#pragma unroll
    for (int ni = 0; ni < 2; ++ni) {
#pragma unroll
      for (int reg = 0; reg < 16; ++reg) {
        int row = o0 + wr * 64 + mi * 32 + (reg & 3) + 8 * (reg >> 2) + 4 * cr;
        out[obase + (size_t)row * HW_ + ni * 32] = acc[mi][ni][reg];
      }
    }
  }
}

extern "C" void kernel_launch(void* const* d_in, const int* in_sizes, int n_in,
                              void* d_out, int out_size, void* d_ws, size_t ws_size,
                              hipStream_t stream) {
  const float* mat0      = (const float*)d_in[0];   // [8,256,64,64]
  const float* mat1      = (const float*)d_in[1];   // [256,256,8]
  const float* mask      = (const float*)d_in[2];   // [8,64,64]
  const float* Alpha     = (const float*)d_in[3];   // [8]
  const int*   use_alpha = (const int*)d_in[4];     // [1]
  (void)in_sizes; (void)n_in; (void)out_size; (void)ws_size;

  _Float16* Aprep = (_Float16*)d_ws;                // 1 MiB scratch
  float* outp  = (float*)d_out;

  prep_w_kernel<<<256, 256, 0, stream>>>(mat1, Alpha, use_alpha, Aprep);
  gemm_deform_kernel<<<512, 256, 0, stream>>>(mat0, Aprep, mask, outp);
}

// Round 12
// 48.578 us; speedup vs baseline: 1.1133x; 1.0434x over previous
//
#include <hip/hip_runtime.h>
#include <hip/hip_bf16.h>
#include <stdint.h>

// out[b,o,p] = sum_{r,c} mat0[b,c,p] * mat1[o,c,r]*Alpha[r] * mask[r,p]
// GEMM: M=256 (o), N=32768 (n=b*4096+p), K=2048 (k=c*8+r).
// A[o,k] = mat1[o,c,r]*Alpha[r]  (prepped FP16 in d_ws, layout [c][o][8r])
// B[k,n] = mat0[b,c,p]*mask[r,p] synthesized IN REGISTERS per lane (fp16).
// Round 12 = R9 + {triple-buffered A slabs, stage 2 rounds ahead, ONE
// vmcnt(12)+barrier per round}. Tests the last un-falsified mechanism:
// staging-DMA latency (~1000+cyc) vs per-half-round cover (~800cyc) and
// barrier density. DMA cover is now ~2 rounds (~6000cyc); vmcnt never
// drains below s(rd+1)+P(rd+1)=12 in flight. COMP identical to R9.

typedef __attribute__((ext_vector_type(8)))  _Float16 half8;
typedef __attribute__((ext_vector_type(16))) float    f32x16;

#define C_IN  256
#define HW_   4096
#define NRND  32    // K rounds of 64 (8 c-planes per round)

__global__ __launch_bounds__(256) void prep_w_kernel(
    const float* __restrict__ mat1, const float* __restrict__ Alpha,
    const int* __restrict__ use_alpha, _Float16* __restrict__ Aprep) {
  int t = blockIdx.x * 256 + threadIdx.x;   // o = t&255, c = t>>8
  int o = t & 255;
  int c = t >> 8;
  int ua = use_alpha[0];
  const float* src = mat1 + ((size_t)o * C_IN + c) * 8;
  half8 v;
#pragma unroll
  for (int r = 0; r < 8; ++r) {
    float s = ua ? Alpha[r] : 1.0f;
    v[r] = (_Float16)(src[r] * s);
  }
  // layout: slot (c*256 + o) holds 8 fp16 (r fastest)
  *(half8*)(Aprep + ((size_t)c * 256 + o) * 8) = v;
}

__global__ __launch_bounds__(256, 2) void gemm_deform_kernel(
    const float* __restrict__ mat0, const _Float16* __restrict__ Aprep,
    const float* __restrict__ mask, float* __restrict__ out) {
  // A slab per round: 8 c-planes x 128 rows, slot = cq*128 + (o-o0), 16B
  __shared__ half8 A_lds[3][1024];   // 3 x 16 KiB ring

  int bid = blockIdx.x;
  int wg = (bid & 7) * 64 + (bid >> 3);   // XCD swizzle (512%8==0, bijective)
  int tile_m = wg & 1;                    // M fastest: pair shares mat0 cols
  int tile_n = wg >> 1;                   // 0..255
  int o0 = tile_m * 128;
  int n0 = tile_n * 128;
  int b  = n0 >> 12;
  int p0 = n0 & 4095;

  int t    = threadIdx.x;
  int lane = t & 63;
  int w    = t >> 6;        // 0..3
  int wc   = w & 1;         // N-half (64 cols)
  int wr   = w >> 1;        // M-half (64 rows)
  int l31  = lane & 31;
  int cr   = lane >> 5;     // c-plane parity within MFMA K=16

  // this wave's two 32-col groups; lane-resident packed fp16 mask
  int colb = p0 + wc * 64 + l31;
  half8 mkh[2];
#pragma unroll
  for (int ni = 0; ni < 2; ++ni)
#pragma unroll
    for (int r = 0; r < 8; ++r)
      mkh[ni][r] = (_Float16)mask[r * HW_ + colb + ni * 32];

  // mat0 scalar source: plane c = rd*8 + kq*2 + cr, columns colb, colb+32
  const float* __restrict__ m0b =
      mat0 + ((size_t)b * C_IN + cr) * HW_ + colb;

  // A staging: global slot (16B units) in Aprep; LDS dest wave-uniform base
  const __attribute__((address_space(1))) uint32_t* gA =
      (const __attribute__((address_space(1))) uint32_t*)Aprep;
  __attribute__((address_space(3))) uint32_t* lA =
      (__attribute__((address_space(3))) uint32_t*)&A_lds[0][0];
  int soo  = (w & 1) * 64 + lane;   // column part of this thread's src slot
  int scqb = w >> 1;                // c-plane parity of this thread's src slot

  f32x16 acc[2][2];   // [mi][ni]
#pragma unroll
  for (int mi = 0; mi < 2; ++mi)
#pragma unroll
    for (int ni = 0; ni < 2; ++ni)
#pragma unroll
      for (int j = 0; j < 16; ++j) acc[mi][ni][j] = 0.f;

  float P0[4][2], P1[4][2];   // [kq][ni] mat0 scalars, ping-pong by parity

  auto STAGE = [&](int rd, int buf) {   // 4 global_load_lds (vmcnt +4)
#pragma unroll
    for (int i = 0; i < 4; ++i) {
      int gslot = (rd * 8 + i * 2 + scqb) * 256 + o0 + soo;
      __builtin_amdgcn_global_load_lds(gA + (size_t)gslot * 4,
                                       lA + (size_t)(buf * 1024 + i * 256 + w * 64) * 4,
                                       16, 0, 0);
    }
  };

  auto LOADP = [&](float (&P)[4][2], int rd) {   // 8 loads (vmcnt +8)
    const float* mp = m0b + (size_t)(rd * 8) * HW_;
#pragma unroll
    for (int kq = 0; kq < 4; ++kq) {
      P[kq][0] = mp[(size_t)(kq * 2) * HW_];
      P[kq][1] = mp[(size_t)(kq * 2) * HW_ + 32];
    }
  };

  // compute round rd from A_lds slab; refill P for round rd+2 (clamped)
  auto COMP = [&](const half8* __restrict__ Abuf, float (&P)[4][2], int rd) {
    int rp = rd + 2 > 31 ? 31 : rd + 2;
    const float* mnext = m0b + (size_t)(rp * 8) * HW_;
#pragma unroll
    for (int kq = 0; kq < 4; ++kq) {
      half8 a0 = Abuf[(kq * 2 + cr) * 128 + wr * 64 + l31];
      half8 a1 = Abuf[(kq * 2 + cr) * 128 + wr * 64 + 32 + l31];
      _Float16 h0 = (_Float16)P[kq][0];
      _Float16 h1 = (_Float16)P[kq][1];
      half8 pb0 = {h0, h0, h0, h0, h0, h0, h0, h0};
      half8 pb1 = {h1, h1, h1, h1, h1, h1, h1, h1};
      half8 bv0 = pb0 * mkh[0];   // 4x v_pk_mul_f16
      half8 bv1 = pb1 * mkh[1];
      acc[0][0] = __builtin_amdgcn_mfma_f32_32x32x16_f16(a0, bv0, acc[0][0], 0, 0, 0);
      acc[0][1] = __builtin_amdgcn_mfma_f32_32x32x16_f16(a0, bv1, acc[0][1], 0, 0, 0);
      acc[1][0] = __builtin_amdgcn_mfma_f32_32x32x16_f16(a1, bv0, acc[1][0], 0, 0, 0);
      acc[1][1] = __builtin_amdgcn_mfma_f32_32x32x16_f16(a1, bv1, acc[1][1], 0, 0, 0);
      // refill this kq's P for round rd+2 (stays in flight across barriers)
      P[kq][0] = mnext[(size_t)(kq * 2) * HW_];
      P[kq][1] = mnext[(size_t)(kq * 2) * HW_ + 32];
    }
  };

  // ---- prologue: order matters for vmcnt FIFO accounting ----
  STAGE(0, 0);       // s0: 4
  LOADP(P0, 0);      // P0: +8 -> 12
  STAGE(1, 1);       // s1: +4 -> 16
  LOADP(P1, 1);      // P1: +8 -> 24

  // ---- main loop: one vmcnt + one barrier per round ----
  // entry state each round: [s(rd)4, P(rd)8, s(rd+1)4, P(rd+1)8] = 24
#pragma unroll 1
  for (int rd = 0; rd < NRND; rd += 2) {
    // even round
    asm volatile("s_waitcnt vmcnt(12)" ::: "memory");   // s(rd)+P(rd) landed
    __builtin_amdgcn_s_barrier();                       // all waves past COMP(rd-1)
    {
      int rs = rd + 2 > 31 ? 31 : rd + 2;
      STAGE(rs, (rd + 2) % 3);                          // overwrite buf(rd-1): safe
      COMP(&A_lds[0][0] + (rd % 3) * 1024, P0, rd);     // refills P0 for rd+2
    }
    // odd round
    asm volatile("s_waitcnt vmcnt(12)" ::: "memory");   // s(rd+1)+P(rd+1) landed
    __builtin_amdgcn_s_barrier();
    {
      int rs = rd + 3 > 31 ? 31 : rd + 3;
      STAGE(rs, (rd + 3) % 3);
      COMP(&A_lds[0][0] + ((rd + 1) % 3) * 1024, P1, rd + 1);
    }
  }

  // ---- epilogue: 32x32 C/D layout col=lane&31, row=(reg&3)+8*(reg>>2)+4*cr ----
  size_t obase = (size_t)b * 256 * HW_ + colb;
#pragma unroll
  for (int mi = 0; mi < 2; ++mi) {
#pragma unroll
    for (int ni = 0; ni < 2; ++ni) {
#pragma unroll
      for (int reg = 0; reg < 16; ++reg) {
        int row = o0 + wr * 64 + mi * 32 + (reg & 3) + 8 * (reg >> 2) + 4 * cr;
        out[obase + (size_t)row * HW_ + ni * 32] = acc[mi][ni][reg];
      }
    }
  }
}

extern "C" void kernel_launch(void* const* d_in, const int* in_sizes, int n_in,
                              void* d_out, int out_size, void* d_ws, size_t ws_size,
                              hipStream_t stream) {
  const float* mat0      = (const float*)d_in[0];   // [8,256,64,64]
  const float* mat1      = (const float*)d_in[1];   // [256,256,8]
  const float* mask      = (const float*)d_in[2];   // [8,64,64]
  const float* Alpha     = (const float*)d_in[3];   // [8]
  const int*   use_alpha = (const int*)d_in[4];     // [1]
  (void)in_sizes; (void)n_in; (void)out_size; (void)ws_size;

  _Float16* Aprep = (_Float16*)d_ws;                // 1 MiB scratch
  float* outp  = (float*)d_out;

  prep_w_kernel<<<256, 256, 0, stream>>>(mat1, Alpha, use_alpha, Aprep);
  gemm_deform_kernel<<<512, 256, 0, stream>>>(mat0, Aprep, mask, outp);
}